// Round 8
// baseline (1561.398 us; speedup 1.0000x reference)
//
#include <hip/hip_runtime.h>
#include <math.h>

namespace {

constexpr int Bb = 4, Ss = 1024, Dd = 1024, Hh = 16, HDim = 64, Nn = 4096;
constexpr int Mm = Bb * Ss; // 4096

// ---------------------------------------------------------------------------
// fp32 GEMM v6: C[M,N] = A[M,K] @ W[N,K]^T (+ bias[N]).
// 256 threads = 4 waves (2x2 quadrants), micro TM x 8.
// TM=8 -> BM=128; TM=4 -> BM=64 (ctx GEMM: 512 blocks -> 2/CU).
// DOUBLE-buffered LDS + ONE barrier per tile: kt's reads of buf[kt&1] and
// kt+2's writes to the same buf are separated by kt+1's barrier (which
// drains lgkmcnt) -> safe. Prefetch for kt+1 issued AFTER the barrier, so
// its implicit vmcnt wait (at kt+1's ds_writes) lands one full compute
// phase after issue -> HBM latency hidden.
// MODE 0: C = acc + bias.  MODE 2 (TM=8): partial[blockIdx.y][n] = max over
// the tile's 128 rows (feeds the router's pooled max).
// ---------------------------------------------------------------------------
template <int MODE, int TM>
__global__ __launch_bounds__(256, 2) void gemm_f32(
    const float* __restrict__ A, const float* __restrict__ W,
    const float* __restrict__ bias, float* __restrict__ C, const int K,
    const int ldc) {
  constexpr int BM = TM * 16;
  __shared__ float As[2][16][BM];
  __shared__ float Ws[2][16][128];
  __shared__ float red[2][128];  // MODE2 cross-wave reduction
  const int tid = threadIdx.x;
  const int lane = tid & 63, wv = tid >> 6;
  const int wm = wv >> 1, wn = wv & 1;
  const int lty = lane >> 3, ltx = lane & 7;
  const int m0 = blockIdx.y * BM, n0 = blockIdx.x * 128;
  const int row0 = wm * (BM / 2) + lty * TM;
  const int col0 = wn * 64 + ltx * 8;
  const int asrow = (TM == 8) ? (tid >> 1) : (tid >> 2);
  const int asoff = (TM == 8) ? ((tid & 1) * 8) : ((tid & 3) * 4);
  const int bsrow = tid >> 1, bsoff = (tid & 1) * 8;
  const float* Ap = A + (size_t)(m0 + asrow) * K + asoff;
  const float* Wp = W + (size_t)(n0 + bsrow) * K + bsoff;

  // preload tile 0
  float4 a0r, a1r, w0r, w1r;
  a0r = *(const float4*)(Ap);
  if constexpr (TM == 8) a1r = *(const float4*)(Ap + 4);
  w0r = *(const float4*)(Wp);
  w1r = *(const float4*)(Wp + 4);

  float acc[TM][8] = {};
  const int NT = K / 16;
#pragma unroll 1
  for (int kt = 0; kt < NT; ++kt) {
    float* Ab = &As[kt & 1][0][0];
    float* Wb = &Ws[kt & 1][0][0];
    // regs -> LDS (transposed [k][m]); implicit vmcnt wait for the regs sits
    // here, one full compute phase after the loads were issued.
    Ab[(asoff + 0) * BM + asrow] = a0r.x;
    Ab[(asoff + 1) * BM + asrow] = a0r.y;
    Ab[(asoff + 2) * BM + asrow] = a0r.z;
    Ab[(asoff + 3) * BM + asrow] = a0r.w;
    if constexpr (TM == 8) {
      Ab[(asoff + 4) * BM + asrow] = a1r.x;
      Ab[(asoff + 5) * BM + asrow] = a1r.y;
      Ab[(asoff + 6) * BM + asrow] = a1r.z;
      Ab[(asoff + 7) * BM + asrow] = a1r.w;
    }
    Wb[(bsoff + 0) * 128 + bsrow] = w0r.x;
    Wb[(bsoff + 1) * 128 + bsrow] = w0r.y;
    Wb[(bsoff + 2) * 128 + bsrow] = w0r.z;
    Wb[(bsoff + 3) * 128 + bsrow] = w0r.w;
    Wb[(bsoff + 4) * 128 + bsrow] = w1r.x;
    Wb[(bsoff + 5) * 128 + bsrow] = w1r.y;
    Wb[(bsoff + 6) * 128 + bsrow] = w1r.z;
    Wb[(bsoff + 7) * 128 + bsrow] = w1r.w;
    __syncthreads();  // tile visible; single barrier per iteration
    if (kt + 1 < NT) {  // issue next-tile loads; consumed after compute
      const int kb = (kt + 1) * 16;
      a0r = *(const float4*)(Ap + kb);
      if constexpr (TM == 8) a1r = *(const float4*)(Ap + kb + 4);
      w0r = *(const float4*)(Wp + kb);
      w1r = *(const float4*)(Wp + kb + 4);
    }
#pragma unroll
    for (int kk = 0; kk < 16; ++kk) {
      float4 aq0 = *(const float4*)&Ab[kk * BM + row0];
      float4 aq1;
      if constexpr (TM == 8) aq1 = *(const float4*)&Ab[kk * BM + row0 + 4];
      float4 bq0 = *(const float4*)&Wb[kk * 128 + col0];
      float4 bq1 = *(const float4*)&Wb[kk * 128 + col0 + 4];
      float av[TM];
      av[0] = aq0.x; av[1] = aq0.y; av[2] = aq0.z; av[3] = aq0.w;
      if constexpr (TM == 8) {
        av[4] = aq1.x; av[5] = aq1.y; av[6] = aq1.z; av[7] = aq1.w;
      }
      const float bv[8] = {bq0.x, bq0.y, bq0.z, bq0.w,
                           bq1.x, bq1.y, bq1.z, bq1.w};
#pragma unroll
      for (int i = 0; i < TM; ++i)
#pragma unroll
        for (int j = 0; j < 8; ++j)
          acc[i][j] = fmaf(av[i], bv[j], acc[i][j]);
    }
  }

  if constexpr (MODE == 0) {
    float4 bb0 = *(const float4*)&bias[n0 + col0];
    float4 bb1 = *(const float4*)&bias[n0 + col0 + 4];
    const float bvv[8] = {bb0.x, bb0.y, bb0.z, bb0.w,
                          bb1.x, bb1.y, bb1.z, bb1.w};
#pragma unroll
    for (int i = 0; i < TM; ++i) {
      float* crow = C + (size_t)(m0 + row0 + i) * ldc + n0 + col0;
      float4 o0 = {acc[i][0] + bvv[0], acc[i][1] + bvv[1],
                   acc[i][2] + bvv[2], acc[i][3] + bvv[3]};
      float4 o1 = {acc[i][4] + bvv[4], acc[i][5] + bvv[5],
                   acc[i][6] + bvv[6], acc[i][7] + bvv[7]};
      *(float4*)(crow) = o0;
      *(float4*)(crow + 4) = o1;
    }
  } else {
    float cm[8];
#pragma unroll
    for (int j = 0; j < 8; ++j) {
      float m = acc[0][j];
#pragma unroll
      for (int i = 1; i < TM; ++i) m = fmaxf(m, acc[i][j]);
      m = fmaxf(m, __shfl_xor(m, 8));   // reduce over lty (lane bits 3..5)
      m = fmaxf(m, __shfl_xor(m, 16));
      m = fmaxf(m, __shfl_xor(m, 32));
      cm[j] = m;
    }
    __syncthreads();
    if (lty == 0) {
      float4 c0 = {cm[0], cm[1], cm[2], cm[3]};
      float4 c1 = {cm[4], cm[5], cm[6], cm[7]};
      *(float4*)&red[wm][wn * 64 + ltx * 8] = c0;
      *(float4*)&red[wm][wn * 64 + ltx * 8 + 4] = c1;
    }
    __syncthreads();
    if (tid < 128)
      C[(size_t)blockIdx.y * ldc + n0 + tid] =
          fmaxf(red[0][tid], red[1][tid]);
  }
}

// ---------------------------------------------------------------------------
// Flash attention v4 (fixed), fp32: ONE wave per block, ZERO barriers.
// QBLK=64, KVBLK=32, all LDS wave-private; within-wave DS ops are issued
// in program order and the K/P alias is visible lane-locally, so the
// compiler cannot reorder across it -> RAW/WAR safe without __syncthreads.
// K buffer reused as P after QK^T. K/V reg-prefetched one tile ahead
// (vmcnt wait lands after a full tile of compute).
// r7 BUG FIX: each lane covers a 32-float half-row -> kreg[8]/vreg[8]
// (r7 had [4]: half of every K/V tile was stale LDS -> absmax 4057).
// 4-float-granule XOR swizzle: (r,c) -> c ^ ((((r>>3)^r)&7)<<2); QK/PV
// reads conflict-free (8 distinct granules x 8-lane broadcast).
// LDS = 16+8+8 = 32 KB -> 5 blocks/CU. Grid: (S/64, B*H) = 1024 blocks.
// ---------------------------------------------------------------------------
__device__ __forceinline__ int swz(int r, int c) {
  return c ^ ((((r >> 3) ^ r) & 7) << 2);
}

__global__ __launch_bounds__(64) void attn_kernel(
    const float* __restrict__ qkv, float* __restrict__ ctx) {
  __shared__ float Qs[64][64];   // 16 KB
  __shared__ float KP[32 * 64];  // 8 KB: K [32][64], then P [64][32]
  __shared__ float Vs[32][64];   // 8 KB
  const int lane = threadIdx.x;
  const int rg = lane >> 3, cg = lane & 7;
  const int b = blockIdx.y >> 4, h = blockIdx.y & 15;
  const int q0 = blockIdx.x * 64;
  const size_t rstride = 3 * Dd;
  const float* qb = qkv + (size_t)b * Ss * rstride + h * HDim;
  const float* kb_ = qb + Dd;
  const float* vb_ = qb + 2 * Dd;
  // stage Q (lane -> its row), swizzled
  {
    const float* qr = qb + (size_t)(q0 + lane) * rstride;
#pragma unroll
    for (int c = 0; c < 64; c += 4)
      *(float4*)&Qs[lane][swz(lane, c)] = *(const float4*)(qr + c);
  }
  // K/V prefetch: lane covers row lane>>1, 32-float half (lane&1)*32
  const int krow = lane >> 1, khalf = (lane & 1) * 32;
  float4 kreg[8], vreg[8];
  {
    const float* kp = kb_ + (size_t)krow * rstride + khalf;
    const float* vp = vb_ + (size_t)krow * rstride + khalf;
#pragma unroll
    for (int c = 0; c < 8; ++c) {
      kreg[c] = *(const float4*)(kp + 4 * c);
      vreg[c] = *(const float4*)(vp + 4 * c);
    }
  }
  float O[8][8] = {};
  float mr[8], lr[8];
#pragma unroll
  for (int i = 0; i < 8; ++i) { mr[i] = -INFINITY; lr[i] = 0.f; }

#pragma unroll 1
  for (int kt = 0; kt < Ss; kt += 32) {
    // store K/V tile (in-order DS: prior PV reads of KP(P)/Vs retire first)
#pragma unroll
    for (int c = 0; c < 8; ++c) {
      *(float4*)&KP[krow * 64 + swz(krow, khalf + 4 * c)] = kreg[c];
      *(float4*)&Vs[krow][swz(krow, khalf + 4 * c)] = vreg[c];
    }
    if (kt + 32 < Ss) {  // prefetch next K/V tile
      const float* kp = kb_ + (size_t)(kt + 32 + krow) * rstride + khalf;
      const float* vp = vb_ + (size_t)(kt + 32 + krow) * rstride + khalf;
#pragma unroll
      for (int c = 0; c < 8; ++c) {
        kreg[c] = *(const float4*)(kp + 4 * c);
        vreg[c] = *(const float4*)(vp + 4 * c);
      }
    }
    // ---- QK^T: sc[i][j] = sum_d Q[rg*8+i][d] * K[cg*4+j][d]
    float sc[8][4] = {};
#pragma unroll
    for (int d0 = 0; d0 < HDim; d0 += 4) {
      float4 qa[8], kv[4];
#pragma unroll
      for (int i = 0; i < 8; ++i) {
        const int r = rg * 8 + i;
        qa[i] = *(const float4*)&Qs[r][swz(r, d0)];
      }
#pragma unroll
      for (int j = 0; j < 4; ++j) {
        const int r = cg * 4 + j;
        kv[j] = *(const float4*)&KP[r * 64 + swz(r, d0)];
      }
#pragma unroll
      for (int i = 0; i < 8; ++i)
#pragma unroll
        for (int j = 0; j < 4; ++j) {
          sc[i][j] = fmaf(qa[i].x, kv[j].x, sc[i][j]);
          sc[i][j] = fmaf(qa[i].y, kv[j].y, sc[i][j]);
          sc[i][j] = fmaf(qa[i].z, kv[j].z, sc[i][j]);
          sc[i][j] = fmaf(qa[i].w, kv[j].w, sc[i][j]);
        }
    }
    // ---- online softmax (row r; k-slice cg*4..+3; reduce over cg = lane
    // bits 0..2); write P into KP (overwrites K; lane-local alias keeps
    // compiler order, wave-uniform issue keeps HW order)
#pragma unroll
    for (int i = 0; i < 8; ++i) {
      const float s0 = sc[i][0] * 0.125f, s1 = sc[i][1] * 0.125f;
      const float s2 = sc[i][2] * 0.125f, s3 = sc[i][3] * 0.125f;
      float tm = fmaxf(fmaxf(s0, s1), fmaxf(s2, s3));
      tm = fmaxf(tm, __shfl_xor(tm, 1));
      tm = fmaxf(tm, __shfl_xor(tm, 2));
      tm = fmaxf(tm, __shfl_xor(tm, 4));
      const float mnew = fmaxf(mr[i], tm);
      const float p0 = __expf(s0 - mnew), p1 = __expf(s1 - mnew);
      const float p2 = __expf(s2 - mnew), p3 = __expf(s3 - mnew);
      float rs = p0 + p1 + p2 + p3;
      rs += __shfl_xor(rs, 1);
      rs += __shfl_xor(rs, 2);
      rs += __shfl_xor(rs, 4);
      const float corr = __expf(mr[i] - mnew);
      lr[i] = lr[i] * corr + rs;
      mr[i] = mnew;
#pragma unroll
      for (int c = 0; c < 8; ++c) O[i][c] *= corr;
      const int r = rg * 8 + i;
      float4 pv = {p0, p1, p2, p3};
      *(float4*)&KP[r * 32 + swz(r, cg * 4)] = pv;
    }
    // ---- PV: O[i][c] += sum_k P[r][k] * V[k][cg*8+c]
#pragma unroll
    for (int k0 = 0; k0 < 32; k0 += 4) {
      float4 pa[8];
#pragma unroll
      for (int i = 0; i < 8; ++i) {
        const int r = rg * 8 + i;
        pa[i] = *(const float4*)&KP[r * 32 + swz(r, k0)];
      }
#pragma unroll
      for (int jj = 0; jj < 4; ++jj) {
        const int vr = k0 + jj;
        const float4 v0 = *(const float4*)&Vs[vr][swz(vr, cg * 8)];
        const float4 v1 = *(const float4*)&Vs[vr][swz(vr, cg * 8 + 4)];
#pragma unroll
        for (int i = 0; i < 8; ++i) {
          const float p = (jj == 0) ? pa[i].x
                          : (jj == 1) ? pa[i].y
                          : (jj == 2) ? pa[i].z : pa[i].w;
          O[i][0] = fmaf(p, v0.x, O[i][0]);
          O[i][1] = fmaf(p, v0.y, O[i][1]);
          O[i][2] = fmaf(p, v0.z, O[i][2]);
          O[i][3] = fmaf(p, v0.w, O[i][3]);
          O[i][4] = fmaf(p, v1.x, O[i][4]);
          O[i][5] = fmaf(p, v1.y, O[i][5]);
          O[i][6] = fmaf(p, v1.z, O[i][6]);
          O[i][7] = fmaf(p, v1.w, O[i][7]);
        }
      }
    }
  }
#pragma unroll
  for (int i = 0; i < 8; ++i) {
    const float inv = 1.0f / lr[i];
    float* orow =
        ctx + ((size_t)(b * Ss + q0 + rg * 8 + i)) * Dd + h * HDim + cg * 8;
    float4 o0 = {O[i][0] * inv, O[i][1] * inv, O[i][2] * inv, O[i][3] * inv};
    float4 o1 = {O[i][4] * inv, O[i][5] * inv, O[i][6] * inv, O[i][7] * inv};
    *(float4*)(orow) = o0;
    *(float4*)(orow + 4) = o1;
  }
}

// ---------------------------------------------------------------------------
// Router: bitonic full-sort of packed u64 keys (exact stable top-k).
// ---------------------------------------------------------------------------
__device__ inline unsigned int f2s(float f) {
  unsigned int u = __float_as_uint(f);
  return (u >> 31) ? ~u : (u | 0x80000000u);
}
__device__ inline float s2f(unsigned int s) {
  unsigned int u = (s >> 31) ? (s & 0x7fffffffu) : ~s;
  return __uint_as_float(u);
}

__global__ __launch_bounds__(256) void router_kernel(
    const float* __restrict__ partial, const float* __restrict__ aff_b,
    const int* __restrict__ kp, float* __restrict__ out, int out_size) {
  __shared__ unsigned long long keys[Nn];  // 32 KB
  __shared__ float lorig[Nn];              // 16 KB
  __shared__ float rv[4];
  const int tid = threadIdx.x;
  const int b = blockIdx.x;
  const int kcount = *kp;
  float* idx_out = out;
  float* w_out = out + (out_size - Mm * Dd - Bb * Nn);
  for (int n = tid; n < Nn; n += 256) {
    float m = partial[(size_t)(b * 8) * Nn + n];
#pragma unroll
    for (int t = 1; t < 8; ++t)
      m = fmaxf(m, partial[(size_t)(b * 8 + t) * Nn + n]);
    float lg = (m + aff_b[n]) * 0.5f;  // /TEMPERATURE
    lorig[n] = lg;
    keys[n] = ((unsigned long long)f2s(lg) << 32) | (unsigned int)(Nn - 1 - n);
  }
  __syncthreads();
  for (int kk = 2; kk <= Nn; kk <<= 1) {
    for (int j = kk >> 1; j > 0; j >>= 1) {
#pragma unroll 4
      for (int t = tid; t < Nn / 2; t += 256) {
        const int i = 2 * j * (t / j) + (t % j);
        const int p = i + j;
        const bool desc = ((i & kk) == 0);
        unsigned long long a = keys[i], c = keys[p];
        if (desc ? (a < c) : (a > c)) { keys[i] = c; keys[p] = a; }
      }
      __syncthreads();
    }
  }
  const float gm = s2f((unsigned int)(keys[0] >> 32));
  float se = 0.f;
  for (int n = tid; n < Nn; n += 256) se += expf(lorig[n] - gm);
#pragma unroll
  for (int msk = 1; msk < 64; msk <<= 1) se += __shfl_xor(se, msk);
  if ((tid & 63) == 0) rv[tid >> 6] = se;
  __syncthreads();
  se = rv[0] + rv[1] + rv[2] + rv[3];
  __syncthreads();
  float es = 0.f;
  for (int p = tid; p < kcount; p += 256)
    es += expf(s2f((unsigned int)(keys[p] >> 32)) - gm);
#pragma unroll
  for (int msk = 1; msk < 64; msk <<= 1) es += __shfl_xor(es, msk);
  if ((tid & 63) == 0) rv[tid >> 6] = es;
  __syncthreads();
  es = rv[0] + rv[1] + rv[2] + rv[3];
  const float wd = es / se + 1e-8f;
  for (int n = tid; n < Nn; n += 256) w_out[(size_t)b * Nn + n] = 0.f;
  __syncthreads();
  for (int p = tid; p < kcount; p += 256) {
    const unsigned long long kkey = keys[p];
    const int n = Nn - 1 - (int)(kkey & 0xffffffffu);
    const float val = s2f((unsigned int)(kkey >> 32));
    idx_out[b * kcount + p] = (float)n;
    w_out[(size_t)b * Nn + n] = (expf(val - gm) / se) / wd;
  }
}

}  // namespace

extern "C" void kernel_launch(void* const* d_in, const int* in_sizes, int n_in,
                              void* d_out, int out_size, void* d_ws,
                              size_t ws_size, hipStream_t stream) {
  (void)in_sizes; (void)n_in; (void)ws_size;
  const float* x = (const float*)d_in[0];
  const float* in_proj_w = (const float*)d_in[1];
  const float* in_proj_b = (const float*)d_in[2];
  const float* out_w = (const float*)d_in[3];
  const float* out_b = (const float*)d_in[4];
  const float* aff_w = (const float*)d_in[5];
  const float* aff_b = (const float*)d_in[6];
  const int* kp = (const int*)d_in[7];

  float* qkv = (float*)d_ws;                 // [4096, 3072] = 50.3 MB
  float* ctxws = qkv + (size_t)Mm * 3 * Dd;  // [4096, 1024] = 16.8 MB
  float* partial = ctxws + (size_t)Mm * Dd;  // [32, 4096]   = 0.5 MB

  float* out = (float*)d_out;
  float* ctx_out = out + ((size_t)out_size - (size_t)Mm * Dd);  // context tail

  // 1) qkv = x @ in_proj_w^T + b   (768 blocks)
  gemm_f32<0, 8><<<dim3(3 * Dd / 128, Mm / 128), 256, 0, stream>>>(
      x, in_proj_w, in_proj_b, qkv, Dd, 3 * Dd);
  // 2) attention -> ctxws  (1024 one-wave blocks, barrier-free)
  attn_kernel<<<dim3(Ss / 64, Bb * Hh), 64, 0, stream>>>(qkv, ctxws);
  // 3) context = ctxws @ out_w^T + b  (BM=64 -> 512 blocks)
  gemm_f32<0, 4><<<dim3(Dd / 128, Mm / 64), 256, 0, stream>>>(
      ctxws, out_w, out_b, ctx_out, Dd, Dd);
  // 4) partial[mtile][n] = max over 128 rows of (context @ aff_w^T)
  gemm_f32<2, 8><<<dim3(Nn / 128, Mm / 128), 256, 0, stream>>>(
      ctx_out, aff_w, nullptr, partial, Dd, Nn);
  // 5) router: pooled max, softmax, exact top-k, weights
  router_kernel<<<dim3(Bb), 256, 0, stream>>>(partial, aff_b, kp, out, out_size);
}

// Round 9
// 1511.882 us; speedup vs baseline: 1.0328x; 1.0328x over previous
//
#include <hip/hip_runtime.h>
#include <math.h>

namespace {

constexpr int Bb = 4, Ss = 1024, Dd = 1024, Hh = 16, HDim = 64, Nn = 4096;
constexpr int Mm = Bb * Ss; // 4096

// ---------------------------------------------------------------------------
// fp32 GEMM v6 (validated r8): C[M,N] = A[M,K] @ W[N,K]^T (+ bias[N]).
// 256 threads = 4 waves (2x2 quadrants), micro TM x 8.
// TM=8 -> BM=128; TM=4 -> BM=64 (ctx GEMM: 512 blocks -> 2/CU).
// Double-buffered LDS + ONE barrier per tile; prefetch issued after the
// barrier so its implicit vmcnt wait lands one full compute phase later.
// MODE 0: C = acc + bias.  MODE 2 (TM=8): partial[blockIdx.y][n] = max over
// the tile's 128 rows (feeds the router's pooled max).
// ---------------------------------------------------------------------------
template <int MODE, int TM>
__global__ __launch_bounds__(256, 2) void gemm_f32(
    const float* __restrict__ A, const float* __restrict__ W,
    const float* __restrict__ bias, float* __restrict__ C, const int K,
    const int ldc) {
  constexpr int BM = TM * 16;
  __shared__ float As[2][16][BM];
  __shared__ float Ws[2][16][128];
  __shared__ float red[2][128];  // MODE2 cross-wave reduction
  const int tid = threadIdx.x;
  const int lane = tid & 63, wv = tid >> 6;
  const int wm = wv >> 1, wn = wv & 1;
  const int lty = lane >> 3, ltx = lane & 7;
  const int m0 = blockIdx.y * BM, n0 = blockIdx.x * 128;
  const int row0 = wm * (BM / 2) + lty * TM;
  const int col0 = wn * 64 + ltx * 8;
  const int asrow = (TM == 8) ? (tid >> 1) : (tid >> 2);
  const int asoff = (TM == 8) ? ((tid & 1) * 8) : ((tid & 3) * 4);
  const int bsrow = tid >> 1, bsoff = (tid & 1) * 8;
  const float* Ap = A + (size_t)(m0 + asrow) * K + asoff;
  const float* Wp = W + (size_t)(n0 + bsrow) * K + bsoff;

  float4 a0r, a1r, w0r, w1r;
  a0r = *(const float4*)(Ap);
  if constexpr (TM == 8) a1r = *(const float4*)(Ap + 4);
  w0r = *(const float4*)(Wp);
  w1r = *(const float4*)(Wp + 4);

  float acc[TM][8] = {};
  const int NT = K / 16;
#pragma unroll 1
  for (int kt = 0; kt < NT; ++kt) {
    float* Ab = &As[kt & 1][0][0];
    float* Wb = &Ws[kt & 1][0][0];
    Ab[(asoff + 0) * BM + asrow] = a0r.x;
    Ab[(asoff + 1) * BM + asrow] = a0r.y;
    Ab[(asoff + 2) * BM + asrow] = a0r.z;
    Ab[(asoff + 3) * BM + asrow] = a0r.w;
    if constexpr (TM == 8) {
      Ab[(asoff + 4) * BM + asrow] = a1r.x;
      Ab[(asoff + 5) * BM + asrow] = a1r.y;
      Ab[(asoff + 6) * BM + asrow] = a1r.z;
      Ab[(asoff + 7) * BM + asrow] = a1r.w;
    }
    Wb[(bsoff + 0) * 128 + bsrow] = w0r.x;
    Wb[(bsoff + 1) * 128 + bsrow] = w0r.y;
    Wb[(bsoff + 2) * 128 + bsrow] = w0r.z;
    Wb[(bsoff + 3) * 128 + bsrow] = w0r.w;
    Wb[(bsoff + 4) * 128 + bsrow] = w1r.x;
    Wb[(bsoff + 5) * 128 + bsrow] = w1r.y;
    Wb[(bsoff + 6) * 128 + bsrow] = w1r.z;
    Wb[(bsoff + 7) * 128 + bsrow] = w1r.w;
    __syncthreads();  // tile visible; single barrier per iteration
    if (kt + 1 < NT) {
      const int kb = (kt + 1) * 16;
      a0r = *(const float4*)(Ap + kb);
      if constexpr (TM == 8) a1r = *(const float4*)(Ap + kb + 4);
      w0r = *(const float4*)(Wp + kb);
      w1r = *(const float4*)(Wp + kb + 4);
    }
#pragma unroll
    for (int kk = 0; kk < 16; ++kk) {
      float4 aq0 = *(const float4*)&Ab[kk * BM + row0];
      float4 aq1;
      if constexpr (TM == 8) aq1 = *(const float4*)&Ab[kk * BM + row0 + 4];
      float4 bq0 = *(const float4*)&Wb[kk * 128 + col0];
      float4 bq1 = *(const float4*)&Wb[kk * 128 + col0 + 4];
      float av[TM];
      av[0] = aq0.x; av[1] = aq0.y; av[2] = aq0.z; av[3] = aq0.w;
      if constexpr (TM == 8) {
        av[4] = aq1.x; av[5] = aq1.y; av[6] = aq1.z; av[7] = aq1.w;
      }
      const float bv[8] = {bq0.x, bq0.y, bq0.z, bq0.w,
                           bq1.x, bq1.y, bq1.z, bq1.w};
#pragma unroll
      for (int i = 0; i < TM; ++i)
#pragma unroll
        for (int j = 0; j < 8; ++j)
          acc[i][j] = fmaf(av[i], bv[j], acc[i][j]);
    }
  }

  if constexpr (MODE == 0) {
    float4 bb0 = *(const float4*)&bias[n0 + col0];
    float4 bb1 = *(const float4*)&bias[n0 + col0 + 4];
    const float bvv[8] = {bb0.x, bb0.y, bb0.z, bb0.w,
                          bb1.x, bb1.y, bb1.z, bb1.w};
#pragma unroll
    for (int i = 0; i < TM; ++i) {
      float* crow = C + (size_t)(m0 + row0 + i) * ldc + n0 + col0;
      float4 o0 = {acc[i][0] + bvv[0], acc[i][1] + bvv[1],
                   acc[i][2] + bvv[2], acc[i][3] + bvv[3]};
      float4 o1 = {acc[i][4] + bvv[4], acc[i][5] + bvv[5],
                   acc[i][6] + bvv[6], acc[i][7] + bvv[7]};
      *(float4*)(crow) = o0;
      *(float4*)(crow + 4) = o1;
    }
  } else {
    float cm[8];
#pragma unroll
    for (int j = 0; j < 8; ++j) {
      float m = acc[0][j];
#pragma unroll
      for (int i = 1; i < TM; ++i) m = fmaxf(m, acc[i][j]);
      m = fmaxf(m, __shfl_xor(m, 8));
      m = fmaxf(m, __shfl_xor(m, 16));
      m = fmaxf(m, __shfl_xor(m, 32));
      cm[j] = m;
    }
    __syncthreads();
    if (lty == 0) {
      float4 c0 = {cm[0], cm[1], cm[2], cm[3]};
      float4 c1 = {cm[4], cm[5], cm[6], cm[7]};
      *(float4*)&red[wm][wn * 64 + ltx * 8] = c0;
      *(float4*)&red[wm][wn * 64 + ltx * 8 + 4] = c1;
    }
    __syncthreads();
    if (tid < 128)
      C[(size_t)blockIdx.y * ldc + n0 + tid] =
          fmaxf(red[0][tid], red[1][tid]);
  }
}

// ---------------------------------------------------------------------------
// Flash attention v5 = r8's validated v4 with two resource fixes:
// (1) __launch_bounds__(64, 1): min 1 wave/EU -> VGPR cap 512. r8's default
//     256 cap spilled the K/V prefetch regs every tile: WRITE_SIZE was
//     531 MB (vs 16 MB of real output) -- pure scratch traffic. Live set
//     ~280 VGPR now fits; occupancy is grid-limited at 1 wave/SIMD anyway.
// (2) XCD-locality: 1D grid, id = qt*64 + bh. All 16 q-tiles of a head have
//     ids == bh (mod 8) -> same XCD under round-robin dispatch -> that
//     head's 512 KB K/V stays in the XCD's L2 (was ~3x refetch, 157 MB).
// Structure unchanged: ONE wave per block, ZERO barriers, wave-private LDS,
// in-order DS; K buffer reused as P; K/V reg-prefetched one tile ahead.
// LDS = 32 KB. Grid: 1024 blocks.
// ---------------------------------------------------------------------------
__device__ __forceinline__ int swz(int r, int c) {
  return c ^ ((((r >> 3) ^ r) & 7) << 2);
}

__global__ __launch_bounds__(64, 1) void attn_kernel(
    const float* __restrict__ qkv, float* __restrict__ ctx) {
  __shared__ float Qs[64][64];   // 16 KB
  __shared__ float KP[32 * 64];  // 8 KB: K [32][64], then P [64][32]
  __shared__ float Vs[32][64];   // 8 KB
  const int lane = threadIdx.x;
  const int rg = lane >> 3, cg = lane & 7;
  const int id = blockIdx.x;
  const int qt = id >> 6, bh = id & 63;   // same-bh blocks share XCD (mod 8)
  const int b = bh >> 4, h = bh & 15;
  const int q0 = qt * 64;
  const size_t rstride = 3 * Dd;
  const float* qb = qkv + (size_t)b * Ss * rstride + h * HDim;
  const float* kb_ = qb + Dd;
  const float* vb_ = qb + 2 * Dd;
  // stage Q (lane -> its row), swizzled
  {
    const float* qr = qb + (size_t)(q0 + lane) * rstride;
#pragma unroll
    for (int c = 0; c < 64; c += 4)
      *(float4*)&Qs[lane][swz(lane, c)] = *(const float4*)(qr + c);
  }
  // K/V prefetch: lane covers row lane>>1, 32-float half (lane&1)*32
  const int krow = lane >> 1, khalf = (lane & 1) * 32;
  float4 kreg[8], vreg[8];
  {
    const float* kp = kb_ + (size_t)krow * rstride + khalf;
    const float* vp = vb_ + (size_t)krow * rstride + khalf;
#pragma unroll
    for (int c = 0; c < 8; ++c) {
      kreg[c] = *(const float4*)(kp + 4 * c);
      vreg[c] = *(const float4*)(vp + 4 * c);
    }
  }
  float O[8][8] = {};
  float mr[8], lr[8];
#pragma unroll
  for (int i = 0; i < 8; ++i) { mr[i] = -INFINITY; lr[i] = 0.f; }

#pragma unroll 1
  for (int kt = 0; kt < Ss; kt += 32) {
    // store K/V tile (in-order DS: prior PV reads of KP(P)/Vs retire first)
#pragma unroll
    for (int c = 0; c < 8; ++c) {
      *(float4*)&KP[krow * 64 + swz(krow, khalf + 4 * c)] = kreg[c];
      *(float4*)&Vs[krow][swz(krow, khalf + 4 * c)] = vreg[c];
    }
    if (kt + 32 < Ss) {  // prefetch next K/V tile
      const float* kp = kb_ + (size_t)(kt + 32 + krow) * rstride + khalf;
      const float* vp = vb_ + (size_t)(kt + 32 + krow) * rstride + khalf;
#pragma unroll
      for (int c = 0; c < 8; ++c) {
        kreg[c] = *(const float4*)(kp + 4 * c);
        vreg[c] = *(const float4*)(vp + 4 * c);
      }
    }
    // ---- QK^T: sc[i][j] = sum_d Q[rg*8+i][d] * K[cg*4+j][d]
    float sc[8][4] = {};
#pragma unroll
    for (int d0 = 0; d0 < HDim; d0 += 4) {
      float4 qa[8], kv[4];
#pragma unroll
      for (int i = 0; i < 8; ++i) {
        const int r = rg * 8 + i;
        qa[i] = *(const float4*)&Qs[r][swz(r, d0)];
      }
#pragma unroll
      for (int j = 0; j < 4; ++j) {
        const int r = cg * 4 + j;
        kv[j] = *(const float4*)&KP[r * 64 + swz(r, d0)];
      }
#pragma unroll
      for (int i = 0; i < 8; ++i)
#pragma unroll
        for (int j = 0; j < 4; ++j) {
          sc[i][j] = fmaf(qa[i].x, kv[j].x, sc[i][j]);
          sc[i][j] = fmaf(qa[i].y, kv[j].y, sc[i][j]);
          sc[i][j] = fmaf(qa[i].z, kv[j].z, sc[i][j]);
          sc[i][j] = fmaf(qa[i].w, kv[j].w, sc[i][j]);
        }
    }
    // ---- online softmax; write P into KP (lane-local alias keeps compiler
    // order, wave-uniform in-order DS issue keeps HW order)
#pragma unroll
    for (int i = 0; i < 8; ++i) {
      const float s0 = sc[i][0] * 0.125f, s1 = sc[i][1] * 0.125f;
      const float s2 = sc[i][2] * 0.125f, s3 = sc[i][3] * 0.125f;
      float tm = fmaxf(fmaxf(s0, s1), fmaxf(s2, s3));
      tm = fmaxf(tm, __shfl_xor(tm, 1));
      tm = fmaxf(tm, __shfl_xor(tm, 2));
      tm = fmaxf(tm, __shfl_xor(tm, 4));
      const float mnew = fmaxf(mr[i], tm);
      const float p0 = __expf(s0 - mnew), p1 = __expf(s1 - mnew);
      const float p2 = __expf(s2 - mnew), p3 = __expf(s3 - mnew);
      float rs = p0 + p1 + p2 + p3;
      rs += __shfl_xor(rs, 1);
      rs += __shfl_xor(rs, 2);
      rs += __shfl_xor(rs, 4);
      const float corr = __expf(mr[i] - mnew);
      lr[i] = lr[i] * corr + rs;
      mr[i] = mnew;
#pragma unroll
      for (int c = 0; c < 8; ++c) O[i][c] *= corr;
      const int r = rg * 8 + i;
      float4 pv = {p0, p1, p2, p3};
      *(float4*)&KP[r * 32 + swz(r, cg * 4)] = pv;
    }
    // ---- PV: O[i][c] += sum_k P[r][k] * V[k][cg*8+c]
#pragma unroll
    for (int k0 = 0; k0 < 32; k0 += 4) {
      float4 pa[8];
#pragma unroll
      for (int i = 0; i < 8; ++i) {
        const int r = rg * 8 + i;
        pa[i] = *(const float4*)&KP[r * 32 + swz(r, k0)];
      }
#pragma unroll
      for (int jj = 0; jj < 4; ++jj) {
        const int vr = k0 + jj;
        const float4 v0 = *(const float4*)&Vs[vr][swz(vr, cg * 8)];
        const float4 v1 = *(const float4*)&Vs[vr][swz(vr, cg * 8 + 4)];
#pragma unroll
        for (int i = 0; i < 8; ++i) {
          const float p = (jj == 0) ? pa[i].x
                          : (jj == 1) ? pa[i].y
                          : (jj == 2) ? pa[i].z : pa[i].w;
          O[i][0] = fmaf(p, v0.x, O[i][0]);
          O[i][1] = fmaf(p, v0.y, O[i][1]);
          O[i][2] = fmaf(p, v0.z, O[i][2]);
          O[i][3] = fmaf(p, v0.w, O[i][3]);
          O[i][4] = fmaf(p, v1.x, O[i][4]);
          O[i][5] = fmaf(p, v1.y, O[i][5]);
          O[i][6] = fmaf(p, v1.z, O[i][6]);
          O[i][7] = fmaf(p, v1.w, O[i][7]);
        }
      }
    }
  }
#pragma unroll
  for (int i = 0; i < 8; ++i) {
    const float inv = 1.0f / lr[i];
    float* orow =
        ctx + ((size_t)(b * Ss + q0 + rg * 8 + i)) * Dd + h * HDim + cg * 8;
    float4 o0 = {O[i][0] * inv, O[i][1] * inv, O[i][2] * inv, O[i][3] * inv};
    float4 o1 = {O[i][4] * inv, O[i][5] * inv, O[i][6] * inv, O[i][7] * inv};
    *(float4*)(orow) = o0;
    *(float4*)(orow + 4) = o1;
  }
}

// ---------------------------------------------------------------------------
// Router: bitonic full-sort of packed u64 keys (exact stable top-k).
// ---------------------------------------------------------------------------
__device__ inline unsigned int f2s(float f) {
  unsigned int u = __float_as_uint(f);
  return (u >> 31) ? ~u : (u | 0x80000000u);
}
__device__ inline float s2f(unsigned int s) {
  unsigned int u = (s >> 31) ? (s & 0x7fffffffu) : ~s;
  return __uint_as_float(u);
}

__global__ __launch_bounds__(256) void router_kernel(
    const float* __restrict__ partial, const float* __restrict__ aff_b,
    const int* __restrict__ kp, float* __restrict__ out, int out_size) {
  __shared__ unsigned long long keys[Nn];  // 32 KB
  __shared__ float lorig[Nn];              // 16 KB
  __shared__ float rv[4];
  const int tid = threadIdx.x;
  const int b = blockIdx.x;
  const int kcount = *kp;
  float* idx_out = out;
  float* w_out = out + (out_size - Mm * Dd - Bb * Nn);
  for (int n = tid; n < Nn; n += 256) {
    float m = partial[(size_t)(b * 8) * Nn + n];
#pragma unroll
    for (int t = 1; t < 8; ++t)
      m = fmaxf(m, partial[(size_t)(b * 8 + t) * Nn + n]);
    float lg = (m + aff_b[n]) * 0.5f;  // /TEMPERATURE
    lorig[n] = lg;
    keys[n] = ((unsigned long long)f2s(lg) << 32) | (unsigned int)(Nn - 1 - n);
  }
  __syncthreads();
  for (int kk = 2; kk <= Nn; kk <<= 1) {
    for (int j = kk >> 1; j > 0; j >>= 1) {
#pragma unroll 4
      for (int t = tid; t < Nn / 2; t += 256) {
        const int i = 2 * j * (t / j) + (t % j);
        const int p = i + j;
        const bool desc = ((i & kk) == 0);
        unsigned long long a = keys[i], c = keys[p];
        if (desc ? (a < c) : (a > c)) { keys[i] = c; keys[p] = a; }
      }
      __syncthreads();
    }
  }
  const float gm = s2f((unsigned int)(keys[0] >> 32));
  float se = 0.f;
  for (int n = tid; n < Nn; n += 256) se += expf(lorig[n] - gm);
#pragma unroll
  for (int msk = 1; msk < 64; msk <<= 1) se += __shfl_xor(se, msk);
  if ((tid & 63) == 0) rv[tid >> 6] = se;
  __syncthreads();
  se = rv[0] + rv[1] + rv[2] + rv[3];
  __syncthreads();
  float es = 0.f;
  for (int p = tid; p < kcount; p += 256)
    es += expf(s2f((unsigned int)(keys[p] >> 32)) - gm);
#pragma unroll
  for (int msk = 1; msk < 64; msk <<= 1) es += __shfl_xor(es, msk);
  if ((tid & 63) == 0) rv[tid >> 6] = es;
  __syncthreads();
  es = rv[0] + rv[1] + rv[2] + rv[3];
  const float wd = es / se + 1e-8f;
  for (int n = tid; n < Nn; n += 256) w_out[(size_t)b * Nn + n] = 0.f;
  __syncthreads();
  for (int p = tid; p < kcount; p += 256) {
    const unsigned long long kkey = keys[p];
    const int n = Nn - 1 - (int)(kkey & 0xffffffffu);
    const float val = s2f((unsigned int)(kkey >> 32));
    idx_out[b * kcount + p] = (float)n;
    w_out[(size_t)b * Nn + n] = (expf(val - gm) / se) / wd;
  }
}

}  // namespace

extern "C" void kernel_launch(void* const* d_in, const int* in_sizes, int n_in,
                              void* d_out, int out_size, void* d_ws,
                              size_t ws_size, hipStream_t stream) {
  (void)in_sizes; (void)n_in; (void)ws_size;
  const float* x = (const float*)d_in[0];
  const float* in_proj_w = (const float*)d_in[1];
  const float* in_proj_b = (const float*)d_in[2];
  const float* out_w = (const float*)d_in[3];
  const float* out_b = (const float*)d_in[4];
  const float* aff_w = (const float*)d_in[5];
  const float* aff_b = (const float*)d_in[6];
  const int* kp = (const int*)d_in[7];

  float* qkv = (float*)d_ws;                 // [4096, 3072] = 50.3 MB
  float* ctxws = qkv + (size_t)Mm * 3 * Dd;  // [4096, 1024] = 16.8 MB
  float* partial = ctxws + (size_t)Mm * Dd;  // [32, 4096]   = 0.5 MB

  float* out = (float*)d_out;
  float* ctx_out = out + ((size_t)out_size - (size_t)Mm * Dd);  // context tail

  // 1) qkv = x @ in_proj_w^T + b   (768 blocks)
  gemm_f32<0, 8><<<dim3(3 * Dd / 128, Mm / 128), 256, 0, stream>>>(
      x, in_proj_w, in_proj_b, qkv, Dd, 3 * Dd);
  // 2) attention -> ctxws  (1024 one-wave blocks, barrier-free, XCD-local)
  attn_kernel<<<dim3(Ss / 64 * Bb * Hh), 64, 0, stream>>>(qkv, ctxws);
  // 3) context = ctxws @ out_w^T + b  (BM=64 -> 512 blocks)
  gemm_f32<0, 4><<<dim3(Dd / 128, Mm / 64), 256, 0, stream>>>(
      ctxws, out_w, out_b, ctx_out, Dd, Dd);
  // 4) partial[mtile][n] = max over 128 rows of (context @ aff_w^T)
  gemm_f32<2, 8><<<dim3(Nn / 128, Mm / 128), 256, 0, stream>>>(
      ctx_out, aff_w, nullptr, partial, Dd, Nn);
  // 5) router: pooled max, softmax, exact top-k, weights
  router_kernel<<<dim3(Bb), 256, 0, stream>>>(partial, aff_b, kp, out, out_size);
}

// Round 10
// 1262.071 us; speedup vs baseline: 1.2372x; 1.1979x over previous
//
#include <hip/hip_runtime.h>
#include <math.h>

namespace {

constexpr int Bb = 4, Ss = 1024, Dd = 1024, Hh = 16, HDim = 64, Nn = 4096;
constexpr int Mm = Bb * Ss; // 4096

__device__ inline void gload_lds16(const void* g, void* l) {
  __builtin_amdgcn_global_load_lds(
      (const __attribute__((address_space(1))) void*)g,
      (__attribute__((address_space(3))) void*)l, 16, 0, 0);
}

// ---------------------------------------------------------------------------
// fp32 GEMM v6 (validated r8/r9): C[M,N] = A[M,K] @ W[N,K]^T (+ bias[N]).
// 256 threads = 4 waves (2x2 quadrants), micro TM x 8.
// Double-buffered LDS + ONE barrier per tile; prefetch issued after the
// barrier so its implicit vmcnt wait lands one full compute phase later.
// MODE 0: C = acc + bias.  MODE 2 (TM=8): partial[blockIdx.y][n] = max over
// the tile's 128 rows (feeds the router's pooled max).
// ---------------------------------------------------------------------------
template <int MODE, int TM>
__global__ __launch_bounds__(256, 2) void gemm_f32(
    const float* __restrict__ A, const float* __restrict__ W,
    const float* __restrict__ bias, float* __restrict__ C, const int K,
    const int ldc) {
  constexpr int BM = TM * 16;
  __shared__ float As[2][16][BM];
  __shared__ float Ws[2][16][128];
  __shared__ float red[2][128];
  const int tid = threadIdx.x;
  const int lane = tid & 63, wv = tid >> 6;
  const int wm = wv >> 1, wn = wv & 1;
  const int lty = lane >> 3, ltx = lane & 7;
  const int m0 = blockIdx.y * BM, n0 = blockIdx.x * 128;
  const int row0 = wm * (BM / 2) + lty * TM;
  const int col0 = wn * 64 + ltx * 8;
  const int asrow = (TM == 8) ? (tid >> 1) : (tid >> 2);
  const int asoff = (TM == 8) ? ((tid & 1) * 8) : ((tid & 3) * 4);
  const int bsrow = tid >> 1, bsoff = (tid & 1) * 8;
  const float* Ap = A + (size_t)(m0 + asrow) * K + asoff;
  const float* Wp = W + (size_t)(n0 + bsrow) * K + bsoff;

  float4 a0r, a1r, w0r, w1r;
  a0r = *(const float4*)(Ap);
  if constexpr (TM == 8) a1r = *(const float4*)(Ap + 4);
  w0r = *(const float4*)(Wp);
  w1r = *(const float4*)(Wp + 4);

  float acc[TM][8] = {};
  const int NT = K / 16;
#pragma unroll 1
  for (int kt = 0; kt < NT; ++kt) {
    float* Ab = &As[kt & 1][0][0];
    float* Wb = &Ws[kt & 1][0][0];
    Ab[(asoff + 0) * BM + asrow] = a0r.x;
    Ab[(asoff + 1) * BM + asrow] = a0r.y;
    Ab[(asoff + 2) * BM + asrow] = a0r.z;
    Ab[(asoff + 3) * BM + asrow] = a0r.w;
    if constexpr (TM == 8) {
      Ab[(asoff + 4) * BM + asrow] = a1r.x;
      Ab[(asoff + 5) * BM + asrow] = a1r.y;
      Ab[(asoff + 6) * BM + asrow] = a1r.z;
      Ab[(asoff + 7) * BM + asrow] = a1r.w;
    }
    Wb[(bsoff + 0) * 128 + bsrow] = w0r.x;
    Wb[(bsoff + 1) * 128 + bsrow] = w0r.y;
    Wb[(bsoff + 2) * 128 + bsrow] = w0r.z;
    Wb[(bsoff + 3) * 128 + bsrow] = w0r.w;
    Wb[(bsoff + 4) * 128 + bsrow] = w1r.x;
    Wb[(bsoff + 5) * 128 + bsrow] = w1r.y;
    Wb[(bsoff + 6) * 128 + bsrow] = w1r.z;
    Wb[(bsoff + 7) * 128 + bsrow] = w1r.w;
    __syncthreads();
    if (kt + 1 < NT) {
      const int kb = (kt + 1) * 16;
      a0r = *(const float4*)(Ap + kb);
      if constexpr (TM == 8) a1r = *(const float4*)(Ap + kb + 4);
      w0r = *(const float4*)(Wp + kb);
      w1r = *(const float4*)(Wp + kb + 4);
    }
#pragma unroll
    for (int kk = 0; kk < 16; ++kk) {
      float4 aq0 = *(const float4*)&Ab[kk * BM + row0];
      float4 aq1;
      if constexpr (TM == 8) aq1 = *(const float4*)&Ab[kk * BM + row0 + 4];
      float4 bq0 = *(const float4*)&Wb[kk * 128 + col0];
      float4 bq1 = *(const float4*)&Wb[kk * 128 + col0 + 4];
      float av[TM];
      av[0] = aq0.x; av[1] = aq0.y; av[2] = aq0.z; av[3] = aq0.w;
      if constexpr (TM == 8) {
        av[4] = aq1.x; av[5] = aq1.y; av[6] = aq1.z; av[7] = aq1.w;
      }
      const float bv[8] = {bq0.x, bq0.y, bq0.z, bq0.w,
                           bq1.x, bq1.y, bq1.z, bq1.w};
#pragma unroll
      for (int i = 0; i < TM; ++i)
#pragma unroll
        for (int j = 0; j < 8; ++j)
          acc[i][j] = fmaf(av[i], bv[j], acc[i][j]);
    }
  }

  if constexpr (MODE == 0) {
    float4 bb0 = *(const float4*)&bias[n0 + col0];
    float4 bb1 = *(const float4*)&bias[n0 + col0 + 4];
    const float bvv[8] = {bb0.x, bb0.y, bb0.z, bb0.w,
                          bb1.x, bb1.y, bb1.z, bb1.w};
#pragma unroll
    for (int i = 0; i < TM; ++i) {
      float* crow = C + (size_t)(m0 + row0 + i) * ldc + n0 + col0;
      float4 o0 = {acc[i][0] + bvv[0], acc[i][1] + bvv[1],
                   acc[i][2] + bvv[2], acc[i][3] + bvv[3]};
      float4 o1 = {acc[i][4] + bvv[4], acc[i][5] + bvv[5],
                   acc[i][6] + bvv[6], acc[i][7] + bvv[7]};
      *(float4*)(crow) = o0;
      *(float4*)(crow + 4) = o1;
    }
  } else {
    float cm[8];
#pragma unroll
    for (int j = 0; j < 8; ++j) {
      float m = acc[0][j];
#pragma unroll
      for (int i = 1; i < TM; ++i) m = fmaxf(m, acc[i][j]);
      m = fmaxf(m, __shfl_xor(m, 8));
      m = fmaxf(m, __shfl_xor(m, 16));
      m = fmaxf(m, __shfl_xor(m, 32));
      cm[j] = m;
    }
    __syncthreads();
    if (lty == 0) {
      float4 c0 = {cm[0], cm[1], cm[2], cm[3]};
      float4 c1 = {cm[4], cm[5], cm[6], cm[7]};
      *(float4*)&red[wm][wn * 64 + ltx * 8] = c0;
      *(float4*)&red[wm][wn * 64 + ltx * 8 + 4] = c1;
    }
    __syncthreads();
    if (tid < 128)
      C[(size_t)blockIdx.y * ldc + n0 + tid] =
          fmaxf(red[0][tid], red[1][tid]);
  }
}

// ---------------------------------------------------------------------------
// Flash attention v6: 4-wave blocks, shared K/V, global_load_lds staging.
// Fixes r9's two residual problems:
//  (1) spills: r9 held K/V prefetch in VGPRs (live ~280 > 256 vector-reg
//      cap -> 270 MB scratch traffic). Now K/V go HBM->LDS directly via
//      global_load_lds (zero VGPR cost); live set ~110 regs -> no spill.
//  (2) occupancy: 1-wave blocks capped residency at 1 wave/SIMD. Now 256-thr
//      blocks (4 waves x 32 q-rows), 56 KB LDS -> 2 blocks/CU = 2 waves/SIMD,
//      and K/V staging+L2 traffic is shared by 4 waves.
// Double-buffered KVBLK=16 tiles; ONE barrier per tile. The barrier's
// mandatory vmcnt drain is exactly the gload completion wait, and the loads
// were issued a full compute phase earlier -> hidden. stage(t+1) writes
// buf^1 while all waves read buf (prev-iter reads retired at last barrier).
// LDS content is XOR-swizzled via pre-swizzled GLOBAL source addresses with
// linear LDS dest (r5-validated pattern); all hot reads conflict-free.
// Grid: 512 = qb*64 + bh -> bh = id mod 64 preserves the r9-validated
// XCD-locality (FETCH 157->33 MB).
// ---------------------------------------------------------------------------
__device__ __forceinline__ int kkey(int r) { return ((r >> 3) ^ r) & 7; }
__device__ __forceinline__ int swz(int r, int c) { return c ^ (kkey(r) << 2); }
__device__ __forceinline__ int swzp(int r, int c) {
  return c ^ ((kkey(r) & 3) << 2);
}

__global__ __launch_bounds__(256, 2) void attn_kernel(
    const float* __restrict__ qkv, float* __restrict__ ctx) {
  __shared__ float Qs[4][32][64];  // 32 KB, wave-private quadrants
  __shared__ float Ks[2][16][64];  // 8 KB, shared, double-buffered
  __shared__ float Vs[2][16][64];  // 8 KB, shared, double-buffered
  __shared__ float Pw[4][32][16];  // 8 KB, wave-private P
  const int tid = threadIdx.x, wv = tid >> 6, lane = tid & 63;
  const int rg = lane >> 3, cg = lane & 7;
  const int id = blockIdx.x;
  const int qb = id >> 6, bh = id & 63;  // bh = id mod 64 -> XCD-local heads
  const int b = bh >> 4, h = bh & 15;
  const int q0 = qb * 128 + wv * 32;
  const size_t rstride = 3 * Dd;
  const float* qbp = qkv + (size_t)b * Ss * rstride + h * HDim;
  const float* kbp = qbp + Dd;
  const float* vbp = qbp + 2 * Dd;

  // stage this wave's Q tile (lane -> row lane>>1, half (lane&1)*32)
  {
    const int r = lane >> 1, ch = (lane & 1) * 32;
    const float* qr = qbp + (size_t)(q0 + r) * rstride + ch;
#pragma unroll
    for (int c = 0; c < 32; c += 4)
      *(float4*)&Qs[wv][r][swz(r, ch + c)] = *(const float4*)(qr + c);
  }

  // K/V tile staging: 8 gload instrs per tile (K:4, V:4), 2 per wave.
  // instr g: rows (g&3)*4..+3 of K (g<4) or V (g>=4); lane l covers
  // dst linear offset l*16B -> row (g&3)*4 + (l>>4), col (l&15)*4;
  // source col pre-swizzled so LDS(r,c') holds X[r][swz(r,c')].
  const int srow = lane >> 4;
  const int scol = (lane & 15) * 4;
#define STAGE_KV(KT, BF)                                                      \
  {                                                                           \
    _Pragma("unroll") for (int j = 0; j < 2; ++j) {                           \
      const int g = wv * 2 + j;                                               \
      const int rr = (g & 3) * 4 + srow;                                      \
      const int cc = swz(rr, scol);                                           \
      if (g < 4)                                                              \
        gload_lds16(kbp + (size_t)((KT) + rr) * rstride + cc,                 \
                    &Ks[BF][(g & 3) * 4][0]);                                 \
      else                                                                    \
        gload_lds16(vbp + (size_t)((KT) + rr) * rstride + cc,                 \
                    &Vs[BF][(g & 3) * 4][0]);                                 \
    }                                                                         \
  }

  STAGE_KV(0, 0);
  __syncthreads();  // prologue: tile 0 visible (drains vmcnt), Q staged

  float O[4][8] = {};
  float mr[4], lr[4];
#pragma unroll
  for (int i = 0; i < 4; ++i) { mr[i] = -INFINITY; lr[i] = 0.f; }

#pragma unroll 1
  for (int t = 0; t < Ss / 16; ++t) {
    const int cur = t & 1;
    if (t + 1 < Ss / 16) STAGE_KV((t + 1) * 16, cur ^ 1);  // async, into buf^1
    // ---- QK^T: sc[i][j] = sum_d Q[rg*4+i][d] * K[cg*2+j][d]
    float sc[4][2] = {};
#pragma unroll
    for (int d0 = 0; d0 < HDim; d0 += 4) {
      float4 qa[4], kv[2];
#pragma unroll
      for (int i = 0; i < 4; ++i) {
        const int r = rg * 4 + i;
        qa[i] = *(const float4*)&Qs[wv][r][swz(r, d0)];
      }
#pragma unroll
      for (int j = 0; j < 2; ++j) {
        const int r = cg * 2 + j;
        kv[j] = *(const float4*)&Ks[cur][r][swz(r, d0)];
      }
#pragma unroll
      for (int i = 0; i < 4; ++i)
#pragma unroll
        for (int j = 0; j < 2; ++j) {
          sc[i][j] = fmaf(qa[i].x, kv[j].x, sc[i][j]);
          sc[i][j] = fmaf(qa[i].y, kv[j].y, sc[i][j]);
          sc[i][j] = fmaf(qa[i].z, kv[j].z, sc[i][j]);
          sc[i][j] = fmaf(qa[i].w, kv[j].w, sc[i][j]);
        }
    }
    // ---- online softmax (rows rg*4+i; 2 cols local; reduce over cg lanes)
#pragma unroll
    for (int i = 0; i < 4; ++i) {
      const float s0 = sc[i][0] * 0.125f, s1 = sc[i][1] * 0.125f;
      float tm = fmaxf(s0, s1);
      tm = fmaxf(tm, __shfl_xor(tm, 1));
      tm = fmaxf(tm, __shfl_xor(tm, 2));
      tm = fmaxf(tm, __shfl_xor(tm, 4));
      const float mnew = fmaxf(mr[i], tm);
      const float p0 = __expf(s0 - mnew), p1 = __expf(s1 - mnew);
      float rs = p0 + p1;
      rs += __shfl_xor(rs, 1);
      rs += __shfl_xor(rs, 2);
      rs += __shfl_xor(rs, 4);
      const float corr = __expf(mr[i] - mnew);
      lr[i] = lr[i] * corr + rs;
      mr[i] = mnew;
#pragma unroll
      for (int c = 0; c < 8; ++c) O[i][c] *= corr;
      const int r = rg * 4 + i;
      float2 pv = {p0, p1};
      *(float2*)&Pw[wv][r][swzp(r, cg * 2)] = pv;  // wave-private, in-order
    }
    // ---- PV: O[i][c] += sum_k P[r][k] * V[k][cg*8+c]
#pragma unroll
    for (int k0 = 0; k0 < 16; k0 += 4) {
      float4 pa[4];
#pragma unroll
      for (int i = 0; i < 4; ++i) {
        const int r = rg * 4 + i;
        pa[i] = *(const float4*)&Pw[wv][r][swzp(r, k0)];
      }
#pragma unroll
      for (int jj = 0; jj < 4; ++jj) {
        const int vr = k0 + jj;
        const float4 v0 = *(const float4*)&Vs[cur][vr][swz(vr, cg * 8)];
        const float4 v1 = *(const float4*)&Vs[cur][vr][swz(vr, cg * 8 + 4)];
#pragma unroll
        for (int i = 0; i < 4; ++i) {
          const float p = (jj == 0) ? pa[i].x
                          : (jj == 1) ? pa[i].y
                          : (jj == 2) ? pa[i].z : pa[i].w;
          O[i][0] = fmaf(p, v0.x, O[i][0]);
          O[i][1] = fmaf(p, v0.y, O[i][1]);
          O[i][2] = fmaf(p, v0.z, O[i][2]);
          O[i][3] = fmaf(p, v0.w, O[i][3]);
          O[i][4] = fmaf(p, v1.x, O[i][4]);
          O[i][5] = fmaf(p, v1.y, O[i][5]);
          O[i][6] = fmaf(p, v1.z, O[i][6]);
          O[i][7] = fmaf(p, v1.w, O[i][7]);
        }
      }
    }
    // ONE barrier: drains this wave's gloads (issued at loop top, hidden by
    // the compute above) and retires all reads of buf[cur] before buf[cur]
    // is overwritten at iteration t+2.
    __syncthreads();
  }
#pragma unroll
  for (int i = 0; i < 4; ++i) {
    const float inv = 1.0f / lr[i];
    float* orow =
        ctx + ((size_t)(b * Ss + q0 + rg * 4 + i)) * Dd + h * HDim + cg * 8;
    float4 o0 = {O[i][0] * inv, O[i][1] * inv, O[i][2] * inv, O[i][3] * inv};
    float4 o1 = {O[i][4] * inv, O[i][5] * inv, O[i][6] * inv, O[i][7] * inv};
    *(float4*)(orow) = o0;
    *(float4*)(orow + 4) = o1;
  }
#undef STAGE_KV
}

// ---------------------------------------------------------------------------
// Router: bitonic full-sort of packed u64 keys (exact stable top-k).
// ---------------------------------------------------------------------------
__device__ inline unsigned int f2s(float f) {
  unsigned int u = __float_as_uint(f);
  return (u >> 31) ? ~u : (u | 0x80000000u);
}
__device__ inline float s2f(unsigned int s) {
  unsigned int u = (s >> 31) ? (s & 0x7fffffffu) : ~s;
  return __uint_as_float(u);
}

__global__ __launch_bounds__(256) void router_kernel(
    const float* __restrict__ partial, const float* __restrict__ aff_b,
    const int* __restrict__ kp, float* __restrict__ out, int out_size) {
  __shared__ unsigned long long keys[Nn];  // 32 KB
  __shared__ float lorig[Nn];              // 16 KB
  __shared__ float rv[4];
  const int tid = threadIdx.x;
  const int b = blockIdx.x;
  const int kcount = *kp;
  float* idx_out = out;
  float* w_out = out + (out_size - Mm * Dd - Bb * Nn);
  for (int n = tid; n < Nn; n += 256) {
    float m = partial[(size_t)(b * 8) * Nn + n];
#pragma unroll
    for (int t = 1; t < 8; ++t)
      m = fmaxf(m, partial[(size_t)(b * 8 + t) * Nn + n]);
    float lg = (m + aff_b[n]) * 0.5f;  // /TEMPERATURE
    lorig[n] = lg;
    keys[n] = ((unsigned long long)f2s(lg) << 32) | (unsigned int)(Nn - 1 - n);
  }
  __syncthreads();
  for (int kk = 2; kk <= Nn; kk <<= 1) {
    for (int j = kk >> 1; j > 0; j >>= 1) {
#pragma unroll 4
      for (int t = tid; t < Nn / 2; t += 256) {
        const int i = 2 * j * (t / j) + (t % j);
        const int p = i + j;
        const bool desc = ((i & kk) == 0);
        unsigned long long a = keys[i], c = keys[p];
        if (desc ? (a < c) : (a > c)) { keys[i] = c; keys[p] = a; }
      }
      __syncthreads();
    }
  }
  const float gm = s2f((unsigned int)(keys[0] >> 32));
  float se = 0.f;
  for (int n = tid; n < Nn; n += 256) se += expf(lorig[n] - gm);
#pragma unroll
  for (int msk = 1; msk < 64; msk <<= 1) se += __shfl_xor(se, msk);
  if ((tid & 63) == 0) rv[tid >> 6] = se;
  __syncthreads();
  se = rv[0] + rv[1] + rv[2] + rv[3];
  __syncthreads();
  float es = 0.f;
  for (int p = tid; p < kcount; p += 256)
    es += expf(s2f((unsigned int)(keys[p] >> 32)) - gm);
#pragma unroll
  for (int msk = 1; msk < 64; msk <<= 1) es += __shfl_xor(es, msk);
  if ((tid & 63) == 0) rv[tid >> 6] = es;
  __syncthreads();
  es = rv[0] + rv[1] + rv[2] + rv[3];
  const float wd = es / se + 1e-8f;
  for (int n = tid; n < Nn; n += 256) w_out[(size_t)b * Nn + n] = 0.f;
  __syncthreads();
  for (int p = tid; p < kcount; p += 256) {
    const unsigned long long kkey2 = keys[p];
    const int n = Nn - 1 - (int)(kkey2 & 0xffffffffu);
    const float val = s2f((unsigned int)(kkey2 >> 32));
    idx_out[b * kcount + p] = (float)n;
    w_out[(size_t)b * Nn + n] = (expf(val - gm) / se) / wd;
  }
}

}  // namespace

extern "C" void kernel_launch(void* const* d_in, const int* in_sizes, int n_in,
                              void* d_out, int out_size, void* d_ws,
                              size_t ws_size, hipStream_t stream) {
  (void)in_sizes; (void)n_in; (void)ws_size;
  const float* x = (const float*)d_in[0];
  const float* in_proj_w = (const float*)d_in[1];
  const float* in_proj_b = (const float*)d_in[2];
  const float* out_w = (const float*)d_in[3];
  const float* out_b = (const float*)d_in[4];
  const float* aff_w = (const float*)d_in[5];
  const float* aff_b = (const float*)d_in[6];
  const int* kp = (const int*)d_in[7];

  float* qkv = (float*)d_ws;                 // [4096, 3072] = 50.3 MB
  float* ctxws = qkv + (size_t)Mm * 3 * Dd;  // [4096, 1024] = 16.8 MB
  float* partial = ctxws + (size_t)Mm * Dd;  // [32, 4096]   = 0.5 MB

  float* out = (float*)d_out;
  float* ctx_out = out + ((size_t)out_size - (size_t)Mm * Dd);  // context tail

  // 1) qkv = x @ in_proj_w^T + b   (768 blocks)
  gemm_f32<0, 8><<<dim3(3 * Dd / 128, Mm / 128), 256, 0, stream>>>(
      x, in_proj_w, in_proj_b, qkv, Dd, 3 * Dd);
  // 2) attention -> ctxws  (512 four-wave blocks, XCD-local)
  attn_kernel<<<dim3(Ss / 128 * Bb * Hh), 256, 0, stream>>>(qkv, ctxws);
  // 3) context = ctxws @ out_w^T + b  (BM=64 -> 512 blocks)
  gemm_f32<0, 4><<<dim3(Dd / 128, Mm / 64), 256, 0, stream>>>(
      ctxws, out_w, out_b, ctx_out, Dd, Dd);
  // 4) partial[mtile][n] = max over 128 rows of (context @ aff_w^T)
  gemm_f32<2, 8><<<dim3(Nn / 128, Mm / 128), 256, 0, stream>>>(
      ctx_out, aff_w, nullptr, partial, Dd, Nn);
  // 5) router: pooled max, softmax, exact top-k, weights
  router_kernel<<<dim3(Bb), 256, 0, stream>>>(partial, aff_b, kp, out, out_size);
}